// Round 22
// baseline (268.330 us; speedup 1.0000x reference)
//
#include <hip/hip_runtime.h>

namespace {

typedef short    v4s __attribute__((ext_vector_type(4)));
typedef float    v4f __attribute__((ext_vector_type(4)));
typedef float    f4  __attribute__((ext_vector_type(4)));
typedef unsigned u2  __attribute__((ext_vector_type(2)));

constexpr int Tt = 512;
constexpr int Dd = 64;
constexpr int CH = 16;            // chunk length (steps)
constexpr float LN2 = 0.69314718055994530942f;

__device__ __forceinline__ unsigned pk_bf16(float a, float b) {
  unsigned ua = __float_as_uint(a), ub = __float_as_uint(b);
  ua += 0x7fffu + ((ua >> 16) & 1u);
  ub += 0x7fffu + ((ub >> 16) & 1u);
  return (ua >> 16) | (ub & 0xffff0000u);
}
__device__ __forceinline__ unsigned pktrunc(float lo, float hi) {
  return __builtin_amdgcn_perm(__float_as_uint(hi), __float_as_uint(lo), 0x07060302u);
}
__device__ __forceinline__ v4s mk4(unsigned lo, unsigned hi) {
  union { unsigned u[2]; v4s s; } z;
  z.u[0] = lo; z.u[1] = hi; return z.s;
}
__device__ __forceinline__ float bf_lo(unsigned u) { return __uint_as_float(u << 16); }
__device__ __forceinline__ float bf_hi(unsigned u) { return __uint_as_float(u & 0xffff0000u); }

__device__ __forceinline__ v4f mfma16(v4s a, v4s b, v4f c) {
  return __builtin_amdgcn_mfma_f32_16x16x16bf16_1k(a, b, c, 0, 0, 0);
}
__device__ __forceinline__ float fexp2(float x) {
#if __has_builtin(__builtin_amdgcn_exp2f)
  return __builtin_amdgcn_exp2f(x);
#else
  return exp2f(x);
#endif
}
__device__ __forceinline__ float rdlane(float v, int idx) {
  return __uint_as_float(__builtin_amdgcn_readlane(__float_as_uint(v), idx));
}

// E LDS index (u2 = 8B units) for (t_local in [0,16), x, wblk)
__device__ __forceinline__ int eidx(int tl, int x, int wblk) {
  return tl * 64 + x * 4 + (wblk ^ (x >> 2));
}

__global__ __launch_bounds__(128, 4) void fhmm_seg(
    const float* __restrict__ seq,     // [B, T, D]
    const int*   __restrict__ lengths, // [B]
    const float* __restrict__ pw,      // [16,16]
    const float* __restrict__ px,      // [16,16]
    const float* __restrict__ py,      // [16,16,64]
    float*       __restrict__ part,    // [2B] per-segment partials (log2)
    u2*          __restrict__ wsdif)   // [16*4*64] B-frag table (32 KB)
{
  const int bid = blockIdx.x;
  const int b   = bid >> 1;
  const int p   = bid & 1;
  const int tid = threadIdx.x;
  const int wv  = tid >> 6;   // 0 = consumer; 1 = producer (all 4 q-tiles)
  const int l   = tid & 63;
  const int g   = l >> 4;
  const int x   = l & 15;

  const int len = lengths[b];
  int mid = ((len + 32) >> 1) & ~15;   // chunk-aligned split point
  if (mid < 32) mid = 32;
  const bool split = (mid < len);

  if (p == 1 && !split) {              // short sequence: p0 does everything
    if (tid == 0) part[bid] = 0.f;
    return;
  }

  __shared__ u2    Elds[2][CH * 64];            // double-buffered E' (2 × 8 KB)
  __shared__ float Mpart[2][CH];                // per-chunk max shifts
  __shared__ __align__(16) float MxT[CH * 20];  // producer-private pad
  // LDS = 16384 + 128 + 1280 = 17792 -> 8 blocks/CU (16 waves/CU)

  const int t_acc  = p ? mid : 0;                    // first accounted step
  const int t_stop = p ? len : (split ? mid : len);  // one-past-last step
  const int c_lo   = p ? ((mid - 32) >> 4) : 0;      // warmup = 2 chunks
  const int c_hi   = (t_stop + 15) >> 4;

  const float* yb = seq + (size_t)b * (Tt * Dd);

  if (wv == 1) {
    // ==================== PRODUCER WAVE (all 4 q-tiles) ====================
    float bfull[16];
#pragma unroll
    for (int st = 0; st < 16; ++st) {
      float pt = 0.f;
#pragma unroll
      for (int c = 0; c < 4; ++c) {
        f4 pv = *(const f4*)(py + (st * 16 + x) * 64 + c * 16 + g * 4);
        float q0 = __log2f(1.f - pv.x), q1 = __log2f(1.f - pv.y),
              q2 = __log2f(1.f - pv.z), q3 = __log2f(1.f - pv.w);
        pt += (q0 + q1) + (q2 + q3);
        u2 wvv;
        wvv.x = pk_bf16(__log2f(pv.x) - q0, __log2f(pv.y) - q1);
        wvv.y = pk_bf16(__log2f(pv.z) - q2, __log2f(pv.w) - q3);
        wsdif[(st * 4 + c) * 64 + l] = wvv;      // all blocks: identical bytes
      }
      pt += __shfl_xor(pt, 16, 64);
      pt += __shfl_xor(pt, 32, 64);
      bfull[st] = pt;                            // base[st*16 + x]
    }

    const v4f z4 = {0.f, 0.f, 0.f, 0.f};
    f4 yv[4];                                    // next-chunk raw y (16 VGPR)

#define YLOAD(TB)                                                             \
    _Pragma("unroll")                                                         \
    for (int c_ = 0; c_ < 4; ++c_)                                            \
      yv[c_] = *(const f4*)(yb + (size_t)((TB) + x) * 64 + c_ * 16 + g * 4);

#define GEMMCHUNK(CHIDX)                                                      \
    {                                                                         \
      const int buf_ = (CHIDX) & 1;                                           \
      v4s ya16[4];                                                            \
      _Pragma("unroll")                                                       \
      for (int c_ = 0; c_ < 4; ++c_)                                          \
        ya16[c_] = mk4(pktrunc(yv[c_].x, yv[c_].y),                           \
                       pktrunc(yv[c_].z, yv[c_].w));                          \
      if ((CHIDX) + 1 < c_hi) { YLOAD(((CHIDX) + 1) * CH) }                   \
      float mx_[4];                                                           \
      _Pragma("unroll")                                                       \
      for (int id_ = 0; id_ < 4; ++id_) mx_[id_] = -1e30f;                    \
      _Pragma("unroll")                                                       \
      for (int q_ = 0; q_ < 4; ++q_) {                                        \
        v4s Bq[16];                                                           \
        _Pragma("unroll")                                                     \
        for (int j_ = 0; j_ < 4; ++j_)                                        \
          _Pragma("unroll")                                                   \
          for (int c_ = 0; c_ < 4; ++c_) {                                    \
            u2 w_ = wsdif[((q_ * 4 + j_) * 4 + c_) * 64 + l];                 \
            Bq[j_ * 4 + c_] = mk4(w_.x, w_.y);                                \
          }                                                                   \
        const float b0_ = bfull[4 * q_ + 0], b1_ = bfull[4 * q_ + 1],         \
                    b2_ = bfull[4 * q_ + 2], b3_ = bfull[4 * q_ + 3];         \
        v4f a0_ = z4, a1_ = z4, a2_ = z4, a3_ = z4;                           \
        _Pragma("unroll")                                                     \
        for (int c_ = 0; c_ < 4; ++c_) {                                      \
          a0_ = mfma16(ya16[c_], Bq[c_],      a0_);                           \
          a1_ = mfma16(ya16[c_], Bq[4 + c_],  a1_);                           \
          a2_ = mfma16(ya16[c_], Bq[8 + c_],  a2_);                           \
          a3_ = mfma16(ya16[c_], Bq[12 + c_], a3_);                           \
        }                                                                     \
        _Pragma("unroll")                                                     \
        for (int id_ = 0; id_ < 4; ++id_) {                                   \
          const float e0_ = a0_[id_] + b0_, e1_ = a1_[id_] + b1_,             \
                      e2_ = a2_[id_] + b2_, e3_ = a3_[id_] + b3_;             \
          u2 wv_;                                                             \
          wv_.x = pk_bf16(e0_, e1_);                                          \
          wv_.y = pk_bf16(e2_, e3_);                                          \
          Elds[buf_][eidx(4 * g + id_, x, q_)] = wv_;                         \
          const float mq_ = fmaxf(fmaxf(e0_, e1_), fmaxf(e2_, e3_));          \
          mx_[id_] = fmaxf(mx_[id_], mq_);                                    \
        }                                                                     \
      }                                                                       \
      _Pragma("unroll")                                                       \
      for (int id_ = 0; id_ < 4; ++id_)                                       \
        MxT[(4 * g + id_) * 20 + x] = mx_[id_];                               \
      {  /* same-wave LDS transpose read (no barrier needed) */               \
        const f4* row_ = (const f4*)&MxT[(l & 15) * 20];                      \
        f4 r0_ = row_[0], r1_ = row_[1], r2_ = row_[2], r3_ = row_[3];        \
        const float m01_ = fmaxf(fmaxf(r0_.x, r0_.y), fmaxf(r0_.z, r0_.w));  \
        const float m23_ = fmaxf(fmaxf(r1_.x, r1_.y), fmaxf(r1_.z, r1_.w));  \
        const float m45_ = fmaxf(fmaxf(r2_.x, r2_.y), fmaxf(r2_.z, r2_.w));  \
        const float m67_ = fmaxf(fmaxf(r3_.x, r3_.y), fmaxf(r3_.z, r3_.w));  \
        const float Mr_ = fmaxf(fmaxf(m01_, m23_), fmaxf(m45_, m67_));        \
        if (l < 16) Mpart[buf_][l] = Mr_;                                     \
      }                                                                       \
    }

    YLOAD(c_lo * CH)
    GEMMCHUNK(c_lo)
    __syncthreads();                       // first buffer ready
#pragma unroll 1
    for (int ch = c_lo; ch < c_hi; ++ch) {
      if (ch + 1 < c_hi) GEMMCHUNK(ch + 1) // overlaps consumer's scan(ch)
      __syncthreads();
    }
#undef GEMMCHUNK
#undef YLOAD

  } else {
    // ==================== CONSUMER WAVE ====================
    __builtin_amdgcn_s_setprio(1);
    v4s pwB, pxB;
    {
      const int r0 = (4 * g) * 16 + x;
      pwB = mk4(pk_bf16(pw[r0], pw[r0 + 16]), pk_bf16(pw[r0 + 32], pw[r0 + 48]));
      pxB = mk4(pk_bf16(px[r0], px[r0 + 16]), pk_bf16(px[r0 + 32], px[r0 + 48]));
    }
    const v4s onesB = mk4(0x3f803f80u, 0x3f803f80u);
    const float p0w0 = pw[4 * g + 0], p0w1 = pw[4 * g + 1],
                p0w2 = pw[4 * g + 2], p0w3 = pw[4 * g + 3];
    const float px0 = px[x];

    float acc  = 0.f;
    float msum = 0.f;
    v4f al;
    al[0] = al[1] = al[2] = al[3] = (p ? 1.f : 0.f);  // p1: uniform warmup init
    const v4f z4 = {0.f, 0.f, 0.f, 0.f};

    __syncthreads();                       // wait first buffer
#pragma unroll 1
    for (int ch = c_lo; ch < c_hi; ++ch) {
      const int tb  = ch * CH;
      const int buf = ch & 1;
      const int te  = (t_stop < tb + CH) ? t_stop : (tb + CH);
      const u2* Eb  = Elds[buf];
      const float accf = (tb >= t_acc) ? 1.0f : 0.0f;  // warmup chunk: 0

      float Mrow = Mpart[buf][l & 15];     // lane l<16 holds M[tb+l]
      if (l < 16) {
        const int tm = tb + l;
        if (tm >= t_acc && tm < t_stop) msum += Mrow;
      }

      int t = tb;
      u2 Ec = Eb[eidx(0, x, g)];

#define SCAN_STEP(TCUR, PF)                                                 \
      {                                                                     \
        u2 En_ = Ec;                                                        \
        PF                                                                  \
        const float Ms_ = rdlane(Mrow, (TCUR) & 15);                        \
        const float e0 = fexp2(bf_lo(Ec.x) - Ms_);                          \
        const float e1 = fexp2(bf_hi(Ec.x) - Ms_);                          \
        const float e2 = fexp2(bf_lo(Ec.y) - Ms_);                          \
        const float e3 = fexp2(bf_hi(Ec.y) - Ms_);                          \
        v4s a16 = mk4(pktrunc(al[0], al[1]), pktrunc(al[2], al[3]));        \
        v4f d1 = mfma16(a16, pwB, z4);                                      \
        v4s d16 = mk4(pktrunc(d1[0], d1[1]), pktrunc(d1[2], d1[3]));        \
        v4f d2 = mfma16(d16, pxB, z4);                                      \
        al[0] = d2[0] * e0; al[1] = d2[1] * e1;                             \
        al[2] = d2[2] * e2; al[3] = d2[3] * e3;                             \
        Ec = En_;                                                           \
      }

#define RENORM                                                              \
      {                                                                     \
        float S = (al[0] + al[1]) + (al[2] + al[3]);                        \
        _Pragma("unroll")                                                   \
        for (int o = 1; o <= 32; o <<= 1) S += __shfl_xor(S, o, 64);        \
        S = fmaxf(S, 1e-35f);                                               \
        const float r = __builtin_amdgcn_rcpf(S);                           \
        al[0] *= r; al[1] *= r; al[2] *= r; al[3] *= r;                     \
        acc += accf * __log2f(S);                                           \
      }

      if (p == 0 && ch == 0) {   // peel t = 0: alpha0 = prior * e
        const float Ms_ = rdlane(Mrow, 0);
        const float e0 = fexp2(bf_lo(Ec.x) - Ms_);
        const float e1 = fexp2(bf_hi(Ec.x) - Ms_);
        const float e2 = fexp2(bf_lo(Ec.y) - Ms_);
        const float e3 = fexp2(bf_hi(Ec.y) - Ms_);
        al[0] = p0w0 * px0 * e0; al[1] = p0w1 * px0 * e1;
        al[2] = p0w2 * px0 * e2; al[3] = p0w3 * px0 * e3;
        t = 1;
        if (t < te) Ec = Eb[eidx(1, x, g)];
      }

      while (t < te && (t & 7)) {     // guarded entry until 8-aligned
        SCAN_STEP(t,
          if (t + 1 < te) { En_ = Eb[eidx((t + 1) & 15, x, g)]; })
        if ((t & 7) == 7) RENORM
        ++t;
      }

      // fast path: 8-step groups, 3-deep E prefetch, MFMA-pipelined renorm
      const int ng = (te - t) >> 3;
      if (ng > 0) {
        u2 E1 = Eb[eidx((t + 1) & 15, x, g)];
        u2 E2 = Eb[eidx((t + 2) & 15, x, g)];
        float Sready = 1.0f, rdy = 1.0f;
        v4f sm1 = z4, sm2 = z4;
        v4s sb = onesB;
#pragma unroll 1
        for (int gi = 0; gi < ng; ++gi) {
#pragma unroll
          for (int k = 0; k < 8; ++k) {
            u2 E3 = Eb[eidx((t + k + 3) & 15, x, g)];   // 3-deep prefetch
            const float Ms_ = rdlane(Mrow, (t + k) & 15);
            float e0 = fexp2(bf_lo(Ec.x) - Ms_);
            float e1 = fexp2(bf_hi(Ec.x) - Ms_);
            float e2 = fexp2(bf_lo(Ec.y) - Ms_);
            float e3 = fexp2(bf_hi(Ec.y) - Ms_);
            if (k == 0) {       // apply previous group's renorm (off chain)
              e0 *= rdy; e1 *= rdy; e2 *= rdy; e3 *= rdy;
              acc += accf * __log2f(Sready);
            }
            v4s a16 = mk4(pktrunc(al[0], al[1]), pktrunc(al[2], al[3]));
            if (k == 1) sm1 = mfma16(a16, onesB, z4);   // S stage 1
            v4f d1 = mfma16(a16, pwB, z4);
            if (k == 2) sb = mk4(pktrunc(sm1[0], sm1[1]),
                                 pktrunc(sm1[2], sm1[3]));
            v4s d16 = mk4(pktrunc(d1[0], d1[1]), pktrunc(d1[2], d1[3]));
            if (k == 3) sm2 = mfma16(sb, onesB, z4);    // S stage 2
            v4f d2 = mfma16(d16, pxB, z4);
            if (k == 4) {
              Sready = fmaxf(sm2[0], 1e-35f);
              rdy = __builtin_amdgcn_rcpf(Sready);
            }
            al[0] = d2[0] * e0; al[1] = d2[1] * e1;
            al[2] = d2[2] * e2; al[3] = d2[3] * e3;
            Ec = E1; E1 = E2; E2 = E3;
          }
          t += 8;
        }
        acc += accf * __log2f(Sready);  // flush pending renorm
        al[0] *= rdy; al[1] *= rdy; al[2] *= rdy; al[3] *= rdy;
      }

      while (t < te) {                // guarded tail
        SCAN_STEP(t,
          if (t + 1 < te) { En_ = Eb[eidx((t + 1) & 15, x, g)]; })
        if ((t & 7) == 7) RENORM
        ++t;
      }
#undef SCAN_STEP
#undef RENORM

      __syncthreads();   // scan(ch) done; producer's GEMM(ch+1) done
    }

    // ---------- finalize: final mass always accounted + msum ----------
    float S = (al[0] + al[1]) + (al[2] + al[3]);
#pragma unroll
    for (int o = 1; o <= 32; o <<= 1) S += __shfl_xor(S, o, 64);
    S = fmaxf(S, 1e-35f);
    acc += __log2f(S);

#pragma unroll
    for (int o = 1; o <= 32; o <<= 1) msum += __shfl_xor(msum, o, 64);

    if (l == 0) part[bid] = acc + msum;
  }
}

__global__ void fhmm_reduce(const float* __restrict__ part,
                            float* __restrict__ out) {
  const int i = blockIdx.x * 256 + threadIdx.x;   // 4 blocks x 256 = 1024
  out[i] = LN2 * (part[2 * i] + part[2 * i + 1]);
}

} // namespace

extern "C" void kernel_launch(void* const* d_in, const int* in_sizes, int n_in,
                              void* d_out, int out_size, void* d_ws, size_t ws_size,
                              hipStream_t stream) {
  const float* seq     = (const float*)d_in[0];
  const int*   lengths = (const int*)d_in[1];
  const float* pw      = (const float*)d_in[2];
  const float* px      = (const float*)d_in[3];
  const float* py      = (const float*)d_in[4];
  float*       out     = (float*)d_out;
  u2*          wsdif   = (u2*)d_ws;                         // 32 KB table
  float*       part    = (float*)((char*)d_ws + 32768);     // 8 KB partials

  hipLaunchKernelGGL(fhmm_seg, dim3(2048), dim3(128), 0, stream,
                     seq, lengths, pw, px, py, part, wsdif);
  hipLaunchKernelGGL(fhmm_reduce, dim3(4), dim3(256), 0, stream, part, out);
}

// Round 23
// 112.413 us; speedup vs baseline: 2.3870x; 2.3870x over previous
//
#include <hip/hip_runtime.h>

namespace {

typedef short    v4s __attribute__((ext_vector_type(4)));
typedef float    v4f __attribute__((ext_vector_type(4)));
typedef float    f4  __attribute__((ext_vector_type(4)));
typedef unsigned u2  __attribute__((ext_vector_type(2)));

constexpr int Tt = 512;
constexpr int Dd = 64;
constexpr int CH = 16;            // chunk length (steps)
constexpr float LN2 = 0.69314718055994530942f;

__device__ __forceinline__ unsigned pk_bf16(float a, float b) {
  unsigned ua = __float_as_uint(a), ub = __float_as_uint(b);
  ua += 0x7fffu + ((ua >> 16) & 1u);
  ub += 0x7fffu + ((ub >> 16) & 1u);
  return (ua >> 16) | (ub & 0xffff0000u);
}
__device__ __forceinline__ unsigned pktrunc(float lo, float hi) {
  return __builtin_amdgcn_perm(__float_as_uint(hi), __float_as_uint(lo), 0x07060302u);
}
__device__ __forceinline__ v4s mk4(unsigned lo, unsigned hi) {
  union { unsigned u[2]; v4s s; } z;
  z.u[0] = lo; z.u[1] = hi; return z.s;
}
__device__ __forceinline__ float bf_lo(unsigned u) { return __uint_as_float(u << 16); }
__device__ __forceinline__ float bf_hi(unsigned u) { return __uint_as_float(u & 0xffff0000u); }

__device__ __forceinline__ v4f mfma16(v4s a, v4s b, v4f c) {
  return __builtin_amdgcn_mfma_f32_16x16x16bf16_1k(a, b, c, 0, 0, 0);
}
__device__ __forceinline__ float fexp2(float x) {
#if __has_builtin(__builtin_amdgcn_exp2f)
  return __builtin_amdgcn_exp2f(x);
#else
  return exp2f(x);
#endif
}
__device__ __forceinline__ float rdlane(float v, int idx) {
  return __uint_as_float(__builtin_amdgcn_readlane(__float_as_uint(v), idx));
}

// E LDS index (u2 = 8B units) for (t_local in [0,16), x, wblk)
__device__ __forceinline__ int eidx(int tl, int x, int wblk) {
  return tl * 64 + x * 4 + (wblk ^ (x >> 2));
}

__global__ __launch_bounds__(128, 1) void fhmm_seg(
    const float* __restrict__ seq,     // [B, T, D]
    const int*   __restrict__ lengths, // [B]
    const float* __restrict__ pw,      // [16,16]
    const float* __restrict__ px,      // [16,16]
    const float* __restrict__ py,      // [16,16,64]
    float*       __restrict__ part,    // [2B] per-segment partials (log2)
    u2*          __restrict__ wsdif)   // [16*4*64] B-frag table (32 KB)
{
  const int bid = blockIdx.x;
  const int b   = bid >> 1;
  const int p   = bid & 1;
  const int tid = threadIdx.x;
  const int wv  = tid >> 6;   // 0 = consumer; 1 = producer (all 4 q-tiles)
  const int l   = tid & 63;
  const int g   = l >> 4;
  const int x   = l & 15;

  const int len = lengths[b];
  int mid = ((len + 32) >> 1) & ~15;   // chunk-aligned split point
  if (mid < 32) mid = 32;
  const bool split = (mid < len);

  if (p == 1 && !split) {              // short sequence: p0 does everything
    if (tid == 0) part[bid] = 0.f;
    return;
  }

  __shared__ u2    Elds[2][CH * 64];            // double-buffered E' (2 × 8 KB)
  __shared__ float Mpart[2][CH];                // per-chunk max shifts
  __shared__ __align__(16) float MxT[CH * 20];  // producer-private pad
  // LDS = 16384 + 128 + 1280 = 17792 -> 8 blocks/CU (16 waves/CU)

  const int t_acc  = p ? mid : 0;                    // first accounted step
  const int t_stop = p ? len : (split ? mid : len);  // one-past-last step
  const int c_lo   = p ? ((mid - 32) >> 4) : 0;      // warmup = 2 chunks
  const int c_hi   = (t_stop + 15) >> 4;

  const float* yb = seq + (size_t)b * (Tt * Dd);

  if (wv == 1) {
    // ==================== PRODUCER WAVE (all 4 q-tiles) ====================
    float bfull[16];
#pragma unroll
    for (int st = 0; st < 16; ++st) {
      float pt = 0.f;
#pragma unroll
      for (int c = 0; c < 4; ++c) {
        f4 pv = *(const f4*)(py + (st * 16 + x) * 64 + c * 16 + g * 4);
        float q0 = __log2f(1.f - pv.x), q1 = __log2f(1.f - pv.y),
              q2 = __log2f(1.f - pv.z), q3 = __log2f(1.f - pv.w);
        pt += (q0 + q1) + (q2 + q3);
        u2 wvv;
        wvv.x = pk_bf16(__log2f(pv.x) - q0, __log2f(pv.y) - q1);
        wvv.y = pk_bf16(__log2f(pv.z) - q2, __log2f(pv.w) - q3);
        wsdif[(st * 4 + c) * 64 + l] = wvv;      // all blocks: identical bytes
      }
      pt += __shfl_xor(pt, 16, 64);
      pt += __shfl_xor(pt, 32, 64);
      bfull[st] = pt;                            // base[st*16 + x]
    }

    const v4f z4 = {0.f, 0.f, 0.f, 0.f};
    f4 yv[4];                                    // next-chunk raw y (16 VGPR)

#define YLOAD(TB)                                                             \
    _Pragma("unroll")                                                         \
    for (int c_ = 0; c_ < 4; ++c_)                                            \
      yv[c_] = *(const f4*)(yb + (size_t)((TB) + x) * 64 + c_ * 16 + g * 4);

#define GEMMCHUNK(CHIDX)                                                      \
    {                                                                         \
      const int buf_ = (CHIDX) & 1;                                           \
      v4s ya16[4];                                                            \
      _Pragma("unroll")                                                       \
      for (int c_ = 0; c_ < 4; ++c_)                                          \
        ya16[c_] = mk4(pktrunc(yv[c_].x, yv[c_].y),                           \
                       pktrunc(yv[c_].z, yv[c_].w));                          \
      if ((CHIDX) + 1 < c_hi) { YLOAD(((CHIDX) + 1) * CH) }                   \
      float mx_[4];                                                           \
      _Pragma("unroll")                                                       \
      for (int id_ = 0; id_ < 4; ++id_) mx_[id_] = -1e30f;                    \
      _Pragma("unroll")                                                       \
      for (int q_ = 0; q_ < 4; ++q_) {                                        \
        v4s Bq[16];                                                           \
        _Pragma("unroll")                                                     \
        for (int j_ = 0; j_ < 4; ++j_)                                        \
          _Pragma("unroll")                                                   \
          for (int c_ = 0; c_ < 4; ++c_) {                                    \
            u2 w_ = wsdif[((q_ * 4 + j_) * 4 + c_) * 64 + l];                 \
            Bq[j_ * 4 + c_] = mk4(w_.x, w_.y);                                \
          }                                                                   \
        const float b0_ = bfull[4 * q_ + 0], b1_ = bfull[4 * q_ + 1],         \
                    b2_ = bfull[4 * q_ + 2], b3_ = bfull[4 * q_ + 3];         \
        v4f a0_ = z4, a1_ = z4, a2_ = z4, a3_ = z4;                           \
        _Pragma("unroll")                                                     \
        for (int c_ = 0; c_ < 4; ++c_) {                                      \
          a0_ = mfma16(ya16[c_], Bq[c_],      a0_);                           \
          a1_ = mfma16(ya16[c_], Bq[4 + c_],  a1_);                           \
          a2_ = mfma16(ya16[c_], Bq[8 + c_],  a2_);                           \
          a3_ = mfma16(ya16[c_], Bq[12 + c_], a3_);                           \
        }                                                                     \
        _Pragma("unroll")                                                     \
        for (int id_ = 0; id_ < 4; ++id_) {                                   \
          const float e0_ = a0_[id_] + b0_, e1_ = a1_[id_] + b1_,             \
                      e2_ = a2_[id_] + b2_, e3_ = a3_[id_] + b3_;             \
          u2 wv_;                                                             \
          wv_.x = pk_bf16(e0_, e1_);                                          \
          wv_.y = pk_bf16(e2_, e3_);                                          \
          Elds[buf_][eidx(4 * g + id_, x, q_)] = wv_;                         \
          const float mq_ = fmaxf(fmaxf(e0_, e1_), fmaxf(e2_, e3_));          \
          mx_[id_] = fmaxf(mx_[id_], mq_);                                    \
        }                                                                     \
      }                                                                       \
      _Pragma("unroll")                                                       \
      for (int id_ = 0; id_ < 4; ++id_)                                       \
        MxT[(4 * g + id_) * 20 + x] = mx_[id_];                               \
      {  /* same-wave LDS transpose read (no barrier needed) */               \
        const f4* row_ = (const f4*)&MxT[(l & 15) * 20];                      \
        f4 r0_ = row_[0], r1_ = row_[1], r2_ = row_[2], r3_ = row_[3];        \
        const float m01_ = fmaxf(fmaxf(r0_.x, r0_.y), fmaxf(r0_.z, r0_.w));  \
        const float m23_ = fmaxf(fmaxf(r1_.x, r1_.y), fmaxf(r1_.z, r1_.w));  \
        const float m45_ = fmaxf(fmaxf(r2_.x, r2_.y), fmaxf(r2_.z, r2_.w));  \
        const float m67_ = fmaxf(fmaxf(r3_.x, r3_.y), fmaxf(r3_.z, r3_.w));  \
        const float Mr_ = fmaxf(fmaxf(m01_, m23_), fmaxf(m45_, m67_));        \
        if (l < 16) Mpart[buf_][l] = Mr_;                                     \
      }                                                                       \
    }

    YLOAD(c_lo * CH)
    GEMMCHUNK(c_lo)
    __syncthreads();                       // first buffer ready
#pragma unroll 1
    for (int ch = c_lo; ch < c_hi; ++ch) {
      if (ch + 1 < c_hi) GEMMCHUNK(ch + 1) // overlaps consumer's scan(ch)
      __syncthreads();
    }
#undef GEMMCHUNK
#undef YLOAD

  } else {
    // ==================== CONSUMER WAVE ====================
    __builtin_amdgcn_s_setprio(1);
    v4s pwB, pxB;
    {
      const int r0 = (4 * g) * 16 + x;
      pwB = mk4(pk_bf16(pw[r0], pw[r0 + 16]), pk_bf16(pw[r0 + 32], pw[r0 + 48]));
      pxB = mk4(pk_bf16(px[r0], px[r0 + 16]), pk_bf16(px[r0 + 32], px[r0 + 48]));
    }
    const v4s onesB = mk4(0x3f803f80u, 0x3f803f80u);
    const float p0w0 = pw[4 * g + 0], p0w1 = pw[4 * g + 1],
                p0w2 = pw[4 * g + 2], p0w3 = pw[4 * g + 3];
    const float px0 = px[x];

    float acc  = 0.f;
    float msum = 0.f;
    v4f al;
    al[0] = al[1] = al[2] = al[3] = (p ? 1.f : 0.f);  // p1: uniform warmup init
    const v4f z4 = {0.f, 0.f, 0.f, 0.f};

    __syncthreads();                       // wait first buffer
#pragma unroll 1
    for (int ch = c_lo; ch < c_hi; ++ch) {
      const int tb  = ch * CH;
      const int buf = ch & 1;
      const int te  = (t_stop < tb + CH) ? t_stop : (tb + CH);
      const u2* Eb  = Elds[buf];
      const float accf = (tb >= t_acc) ? 1.0f : 0.0f;  // warmup chunk: 0

      float Mrow = Mpart[buf][l & 15];     // lane l<16 holds M[tb+l]
      if (l < 16) {
        const int tm = tb + l;
        if (tm >= t_acc && tm < t_stop) msum += Mrow;
      }

      int t = tb;
      u2 Ec = Eb[eidx(0, x, g)];

#define SCAN_STEP(TCUR, PF)                                                 \
      {                                                                     \
        u2 En_ = Ec;                                                        \
        PF                                                                  \
        const float Ms_ = rdlane(Mrow, (TCUR) & 15);                        \
        const float e0 = fexp2(bf_lo(Ec.x) - Ms_);                          \
        const float e1 = fexp2(bf_hi(Ec.x) - Ms_);                          \
        const float e2 = fexp2(bf_lo(Ec.y) - Ms_);                          \
        const float e3 = fexp2(bf_hi(Ec.y) - Ms_);                          \
        v4s a16 = mk4(pktrunc(al[0], al[1]), pktrunc(al[2], al[3]));        \
        v4f d1 = mfma16(a16, pwB, z4);                                      \
        v4s d16 = mk4(pktrunc(d1[0], d1[1]), pktrunc(d1[2], d1[3]));        \
        v4f d2 = mfma16(d16, pxB, z4);                                      \
        al[0] = d2[0] * e0; al[1] = d2[1] * e1;                             \
        al[2] = d2[2] * e2; al[3] = d2[3] * e3;                             \
        Ec = En_;                                                           \
      }

#define RENORM                                                              \
      {                                                                     \
        float S = (al[0] + al[1]) + (al[2] + al[3]);                        \
        _Pragma("unroll")                                                   \
        for (int o = 1; o <= 32; o <<= 1) S += __shfl_xor(S, o, 64);        \
        S = fmaxf(S, 1e-35f);                                               \
        const float r = __builtin_amdgcn_rcpf(S);                           \
        al[0] *= r; al[1] *= r; al[2] *= r; al[3] *= r;                     \
        acc += accf * __log2f(S);                                           \
      }

      if (p == 0 && ch == 0) {   // peel t = 0: alpha0 = prior * e
        const float Ms_ = rdlane(Mrow, 0);
        const float e0 = fexp2(bf_lo(Ec.x) - Ms_);
        const float e1 = fexp2(bf_hi(Ec.x) - Ms_);
        const float e2 = fexp2(bf_lo(Ec.y) - Ms_);
        const float e3 = fexp2(bf_hi(Ec.y) - Ms_);
        al[0] = p0w0 * px0 * e0; al[1] = p0w1 * px0 * e1;
        al[2] = p0w2 * px0 * e2; al[3] = p0w3 * px0 * e3;
        t = 1;
        if (t < te) Ec = Eb[eidx(1, x, g)];
      }

      while (t < te && (t & 7)) {     // guarded entry until 8-aligned
        SCAN_STEP(t,
          if (t + 1 < te) { En_ = Eb[eidx((t + 1) & 15, x, g)]; })
        if ((t & 7) == 7) RENORM
        ++t;
      }

      // fast path: 8-step groups, 3-deep E prefetch, MFMA-pipelined renorm
      const int ng = (te - t) >> 3;
      if (ng > 0) {
        u2 E1 = Eb[eidx((t + 1) & 15, x, g)];
        u2 E2 = Eb[eidx((t + 2) & 15, x, g)];
        float Sready = 1.0f, rdy = 1.0f;
        v4f sm1 = z4, sm2 = z4;
        v4s sb = onesB;
#pragma unroll 1
        for (int gi = 0; gi < ng; ++gi) {
#pragma unroll
          for (int k = 0; k < 8; ++k) {
            u2 E3 = Eb[eidx((t + k + 3) & 15, x, g)];   // 3-deep prefetch
            const float Ms_ = rdlane(Mrow, (t + k) & 15);
            float e0 = fexp2(bf_lo(Ec.x) - Ms_);
            float e1 = fexp2(bf_hi(Ec.x) - Ms_);
            float e2 = fexp2(bf_lo(Ec.y) - Ms_);
            float e3 = fexp2(bf_hi(Ec.y) - Ms_);
            if (k == 0) {       // apply previous group's renorm (off chain)
              e0 *= rdy; e1 *= rdy; e2 *= rdy; e3 *= rdy;
              acc += accf * __log2f(Sready);
            }
            v4s a16 = mk4(pktrunc(al[0], al[1]), pktrunc(al[2], al[3]));
            if (k == 1) sm1 = mfma16(a16, onesB, z4);   // S stage 1
            v4f d1 = mfma16(a16, pwB, z4);
            if (k == 2) sb = mk4(pktrunc(sm1[0], sm1[1]),
                                 pktrunc(sm1[2], sm1[3]));
            v4s d16 = mk4(pktrunc(d1[0], d1[1]), pktrunc(d1[2], d1[3]));
            if (k == 3) sm2 = mfma16(sb, onesB, z4);    // S stage 2
            v4f d2 = mfma16(d16, pxB, z4);
            if (k == 4) {
              Sready = fmaxf(sm2[0], 1e-35f);
              rdy = __builtin_amdgcn_rcpf(Sready);
            }
            al[0] = d2[0] * e0; al[1] = d2[1] * e1;
            al[2] = d2[2] * e2; al[3] = d2[3] * e3;
            Ec = E1; E1 = E2; E2 = E3;
          }
          t += 8;
        }
        acc += accf * __log2f(Sready);  // flush pending renorm
        al[0] *= rdy; al[1] *= rdy; al[2] *= rdy; al[3] *= rdy;
      }

      while (t < te) {                // guarded tail
        SCAN_STEP(t,
          if (t + 1 < te) { En_ = Eb[eidx((t + 1) & 15, x, g)]; })
        if ((t & 7) == 7) RENORM
        ++t;
      }
#undef SCAN_STEP
#undef RENORM

      __syncthreads();   // scan(ch) done; producer's GEMM(ch+1) done
    }

    // ---------- finalize: final mass always accounted + msum ----------
    float S = (al[0] + al[1]) + (al[2] + al[3]);
#pragma unroll
    for (int o = 1; o <= 32; o <<= 1) S += __shfl_xor(S, o, 64);
    S = fmaxf(S, 1e-35f);
    acc += __log2f(S);

#pragma unroll
    for (int o = 1; o <= 32; o <<= 1) msum += __shfl_xor(msum, o, 64);

    if (l == 0) part[bid] = acc + msum;
  }
}

__global__ void fhmm_reduce(const float* __restrict__ part,
                            float* __restrict__ out) {
  const int i = blockIdx.x * 256 + threadIdx.x;   // 4 blocks x 256 = 1024
  out[i] = LN2 * (part[2 * i] + part[2 * i + 1]);
}

} // namespace

extern "C" void kernel_launch(void* const* d_in, const int* in_sizes, int n_in,
                              void* d_out, int out_size, void* d_ws, size_t ws_size,
                              hipStream_t stream) {
  const float* seq     = (const float*)d_in[0];
  const int*   lengths = (const int*)d_in[1];
  const float* pw      = (const float*)d_in[2];
  const float* px      = (const float*)d_in[3];
  const float* py      = (const float*)d_in[4];
  float*       out     = (float*)d_out;
  u2*          wsdif   = (u2*)d_ws;                         // 32 KB table
  float*       part    = (float*)((char*)d_ws + 32768);     // 8 KB partials

  hipLaunchKernelGGL(fhmm_seg, dim3(2048), dim3(128), 0, stream,
                     seq, lengths, pw, px, py, part, wsdif);
  hipLaunchKernelGGL(fhmm_reduce, dim3(4), dim3(256), 0, stream, part, out);
}

// Round 24
// 92.338 us; speedup vs baseline: 2.9059x; 1.2174x over previous
//
#include <hip/hip_runtime.h>

namespace {

typedef short    v4s __attribute__((ext_vector_type(4)));
typedef float    v4f __attribute__((ext_vector_type(4)));
typedef float    f4  __attribute__((ext_vector_type(4)));
typedef unsigned u2  __attribute__((ext_vector_type(2)));

constexpr int Tt = 512;
constexpr int Dd = 64;
constexpr int CH = 32;            // chunk length (steps)
constexpr float LN2 = 0.69314718055994530942f;

__device__ __forceinline__ unsigned pk_bf16(float a, float b) {
  unsigned ua = __float_as_uint(a), ub = __float_as_uint(b);
  ua += 0x7fffu + ((ua >> 16) & 1u);
  ub += 0x7fffu + ((ub >> 16) & 1u);
  return (ua >> 16) | (ub & 0xffff0000u);
}
__device__ __forceinline__ unsigned pktrunc(float lo, float hi) {
  return __builtin_amdgcn_perm(__float_as_uint(hi), __float_as_uint(lo), 0x07060302u);
}
__device__ __forceinline__ v4s mk4(unsigned lo, unsigned hi) {
  union { unsigned u[2]; v4s s; } z;
  z.u[0] = lo; z.u[1] = hi; return z.s;
}
__device__ __forceinline__ float bf_lo(unsigned u) { return __uint_as_float(u << 16); }
__device__ __forceinline__ float bf_hi(unsigned u) { return __uint_as_float(u & 0xffff0000u); }

__device__ __forceinline__ v4f mfma16(v4s a, v4s b, v4f c) {
  return __builtin_amdgcn_mfma_f32_16x16x16bf16_1k(a, b, c, 0, 0, 0);
}
__device__ __forceinline__ float fexp2(float x) {
#if __has_builtin(__builtin_amdgcn_exp2f)
  return __builtin_amdgcn_exp2f(x);
#else
  return exp2f(x);
#endif
}
__device__ __forceinline__ float rdlane(float v, int idx) {
  return __uint_as_float(__builtin_amdgcn_readlane(__float_as_uint(v), idx));
}

// E LDS index (u2 = 8B units) for (t_local in [0,32), x, wblk)
__device__ __forceinline__ int eidx(int tl, int x, int wblk) {
  return tl * 64 + x * 4 + (wblk ^ (x >> 2));
}

__global__ __launch_bounds__(128, 1) void fhmm_fwd(
    const float* __restrict__ seq,     // [B, T, D]
    const int*   __restrict__ lengths, // [B]
    const float* __restrict__ pw,      // [16,16]
    const float* __restrict__ px,      // [16,16]
    const float* __restrict__ py,      // [16,16,64]
    float*       __restrict__ out,     // [B]
    u2*          __restrict__ wsdif)   // [16*4*64] B-frag table (shared, 32 KB)
{
  const int b   = blockIdx.x;
  const int tid = threadIdx.x;
  const int wv  = tid >> 6;            // 0 = consumer (scan), 1 = producer (GEMM)
  const int l   = tid & 63;
  const int g   = l >> 4;
  const int x   = l & 15;

  __shared__ u2    Elds[2][CH * 64];           // double-buffered E' (2 × 16 KB)
  __shared__ float Mbufs[2][32];               // per-chunk max shifts
  __shared__ __align__(16) float MxT[CH * 20]; // producer-private transpose pad
  // LDS total = 32768 + 256 + 2560 = 35584 -> 4 blocks/CU (8 waves/CU)

  const int len = lengths[b];
  const int nch = (len + CH - 1) >> 5;
  const float* yb = seq + (size_t)b * (Tt * Dd);

  if (wv == 1) {
    // ==================== PRODUCER WAVE ====================
    float bfull[16];
#pragma unroll
    for (int st = 0; st < 16; ++st) {
      float pt = 0.f;
#pragma unroll
      for (int c = 0; c < 4; ++c) {
        f4 pv = *(const f4*)(py + (st * 16 + x) * 64 + c * 16 + g * 4);
        float q0 = __log2f(1.f - pv.x), q1 = __log2f(1.f - pv.y),
              q2 = __log2f(1.f - pv.z), q3 = __log2f(1.f - pv.w);
        pt += (q0 + q1) + (q2 + q3);
        u2 wvv;
        wvv.x = pk_bf16(__log2f(pv.x) - q0, __log2f(pv.y) - q1);
        wvv.y = pk_bf16(__log2f(pv.z) - q2, __log2f(pv.w) - q3);
        wsdif[(st * 4 + c) * 64 + l] = wvv;   // all blocks write identical bytes
      }
      pt += __shfl_xor(pt, 16, 64);
      pt += __shfl_xor(pt, 32, 64);
      bfull[st] = pt;   // base[st*16 + x]
    }

#define GEMMCHUNK(CHIDX)                                                      \
    {                                                                         \
      const int tb_  = (CHIDX) * CH;                                          \
      const int buf_ = (CHIDX) & 1;                                           \
      v4s ya16[2][4];                                                         \
      _Pragma("unroll")                                                       \
      for (int mt_ = 0; mt_ < 2; ++mt_) {                                     \
        const float* yp_ = yb + (size_t)(tb_ + mt_ * 16 + x) * 64 + g * 4;    \
        f4 y0_ = *(const f4*)(yp_ + 0);                                       \
        f4 y1_ = *(const f4*)(yp_ + 16);                                      \
        f4 y2_ = *(const f4*)(yp_ + 32);                                      \
        f4 y3_ = *(const f4*)(yp_ + 48);                                      \
        ya16[mt_][0] = mk4(pktrunc(y0_.x, y0_.y), pktrunc(y0_.z, y0_.w));     \
        ya16[mt_][1] = mk4(pktrunc(y1_.x, y1_.y), pktrunc(y1_.z, y1_.w));     \
        ya16[mt_][2] = mk4(pktrunc(y2_.x, y2_.y), pktrunc(y2_.z, y2_.w));     \
        ya16[mt_][3] = mk4(pktrunc(y3_.x, y3_.y), pktrunc(y3_.z, y3_.w));     \
      }                                                                       \
      float mx_[2][4];                                                        \
      _Pragma("unroll")                                                       \
      for (int mt_ = 0; mt_ < 2; ++mt_)                                       \
        _Pragma("unroll")                                                     \
        for (int id_ = 0; id_ < 4; ++id_) mx_[mt_][id_] = -1e30f;             \
      _Pragma("unroll")                                                       \
      for (int q_ = 0; q_ < 4; ++q_) {                                        \
        u2 Bq_[16];                                                           \
        _Pragma("unroll")                                                     \
        for (int j_ = 0; j_ < 4; ++j_)                                        \
          _Pragma("unroll")                                                   \
          for (int c_ = 0; c_ < 4; ++c_)                                      \
            Bq_[j_ * 4 + c_] = wsdif[((q_ * 4 + j_) * 4 + c_) * 64 + l];      \
        const float b0_ = bfull[4 * q_ + 0], b1_ = bfull[4 * q_ + 1],         \
                    b2_ = bfull[4 * q_ + 2], b3_ = bfull[4 * q_ + 3];         \
        _Pragma("unroll")                                                     \
        for (int mt_ = 0; mt_ < 2; ++mt_) {                                   \
          v4f a0_ = z4, a1_ = z4, a2_ = z4, a3_ = z4;                         \
          _Pragma("unroll")                                                   \
          for (int c_ = 0; c_ < 4; ++c_) {                                    \
            a0_ = mfma16(ya16[mt_][c_], mk4(Bq_[c_].x,      Bq_[c_].y),      a0_); \
            a1_ = mfma16(ya16[mt_][c_], mk4(Bq_[4 + c_].x,  Bq_[4 + c_].y),  a1_); \
            a2_ = mfma16(ya16[mt_][c_], mk4(Bq_[8 + c_].x,  Bq_[8 + c_].y),  a2_); \
            a3_ = mfma16(ya16[mt_][c_], mk4(Bq_[12 + c_].x, Bq_[12 + c_].y), a3_); \
          }                                                                   \
          _Pragma("unroll")                                                   \
          for (int id_ = 0; id_ < 4; ++id_) {                                 \
            const float e0_ = a0_[id_] + b0_, e1_ = a1_[id_] + b1_,           \
                        e2_ = a2_[id_] + b2_, e3_ = a3_[id_] + b3_;           \
            u2 wv_;                                                           \
            wv_.x = pk_bf16(e0_, e1_);                                        \
            wv_.y = pk_bf16(e2_, e3_);                                        \
            Elds[buf_][eidx(mt_ * 16 + 4 * g + id_, x, q_)] = wv_;            \
            const float mq_ = fmaxf(fmaxf(e0_, e1_), fmaxf(e2_, e3_));        \
            mx_[mt_][id_] = fmaxf(mx_[mt_][id_], mq_);                        \
          }                                                                   \
        }                                                                     \
      }                                                                       \
      _Pragma("unroll")                                                       \
      for (int mt_ = 0; mt_ < 2; ++mt_)                                       \
        _Pragma("unroll")                                                     \
        for (int id_ = 0; id_ < 4; ++id_)                                     \
          MxT[(mt_ * 16 + 4 * g + id_) * 20 + x] = mx_[mt_][id_];             \
      {  /* same-wave LDS transpose read (no barrier needed) */               \
        const f4* row_ = (const f4*)&MxT[(l & 31) * 20];                      \
        f4 r0_ = row_[0], r1_ = row_[1], r2_ = row_[2], r3_ = row_[3];        \
        const float m01_ = fmaxf(fmaxf(r0_.x, r0_.y), fmaxf(r0_.z, r0_.w));  \
        const float m23_ = fmaxf(fmaxf(r1_.x, r1_.y), fmaxf(r1_.z, r1_.w));  \
        const float m45_ = fmaxf(fmaxf(r2_.x, r2_.y), fmaxf(r2_.z, r2_.w));  \
        const float m67_ = fmaxf(fmaxf(r3_.x, r3_.y), fmaxf(r3_.z, r3_.w));  \
        const float Mr_ = fmaxf(fmaxf(m01_, m23_), fmaxf(m45_, m67_));        \
        if (l < 32) Mbufs[buf_][l] = Mr_;                                     \
      }                                                                       \
    }

    const v4f z4 = {0.f, 0.f, 0.f, 0.f};
    GEMMCHUNK(0)
    __syncthreads();                       // buf0 ready
#pragma unroll 1
    for (int ch = 0; ch < nch; ++ch) {
      if (ch + 1 < nch) GEMMCHUNK(ch + 1)  // overlaps consumer's scan(ch)
      __syncthreads();                     // GEMM(ch+1) done & scan(ch) done
    }
#undef GEMMCHUNK

  } else {
    // ==================== CONSUMER WAVE ====================
    v4s pwB, pxB;
    {
      const int r0 = (4 * g) * 16 + x;
      pwB = mk4(pk_bf16(pw[r0], pw[r0 + 16]), pk_bf16(pw[r0 + 32], pw[r0 + 48]));
      pxB = mk4(pk_bf16(px[r0], px[r0 + 16]), pk_bf16(px[r0 + 32], px[r0 + 48]));
    }
    const float p0w0 = pw[4 * g + 0], p0w1 = pw[4 * g + 1],
                p0w2 = pw[4 * g + 2], p0w3 = pw[4 * g + 3];
    const float px0 = px[x];

    float acc  = 0.f;
    float msum = 0.f;
    v4f al = {0.f, 0.f, 0.f, 0.f};
    const v4f z4 = {0.f, 0.f, 0.f, 0.f};

    __syncthreads();                       // wait buf0
#pragma unroll 1
    for (int ch = 0; ch < nch; ++ch) {
      const int tb  = ch * CH;
      const int buf = ch & 1;
      const int te  = (len < tb + CH) ? len : (tb + CH);
      const u2* Eb  = Elds[buf];

      float Mrow = Mbufs[buf][l & 31];     // lane l<32 holds M[tb+l]
      if (l < 32 && tb + l < len) msum += Mrow;

      int t = tb;
      u2 Ec = Eb[eidx(0, x, g)];

#define SCAN_STEP(TCUR, PF)                                                 \
      {                                                                     \
        u2 En_ = Ec;                                                        \
        PF                                                                  \
        const float Ms_ = rdlane(Mrow, (TCUR) & 31);                        \
        const float e0 = fexp2(bf_lo(Ec.x) - Ms_);                          \
        const float e1 = fexp2(bf_hi(Ec.x) - Ms_);                          \
        const float e2 = fexp2(bf_lo(Ec.y) - Ms_);                          \
        const float e3 = fexp2(bf_hi(Ec.y) - Ms_);                          \
        v4s a16 = mk4(pktrunc(al[0], al[1]), pktrunc(al[2], al[3]));        \
        v4f d1 = mfma16(a16, pwB, z4);                                      \
        v4s d16 = mk4(pktrunc(d1[0], d1[1]), pktrunc(d1[2], d1[3]));        \
        v4f d2 = mfma16(d16, pxB, z4);                                      \
        al[0] = d2[0] * e0; al[1] = d2[1] * e1;                             \
        al[2] = d2[2] * e2; al[3] = d2[3] * e3;                             \
        Ec = En_;                                                           \
      }

#define RENORM                                                              \
      {                                                                     \
        float S = (al[0] + al[1]) + (al[2] + al[3]);                        \
        _Pragma("unroll")                                                   \
        for (int o = 1; o <= 32; o <<= 1) S += __shfl_xor(S, o, 64);        \
        S = fmaxf(S, 1e-35f);                                               \
        const float r = __builtin_amdgcn_rcpf(S);                           \
        al[0] *= r; al[1] *= r; al[2] *= r; al[3] *= r;                     \
        acc += __log2f(S);                                                  \
      }

      if (ch == 0) {   // peel t = 0: alpha0 = prior * e
        const float Ms_ = rdlane(Mrow, 0);
        const float e0 = fexp2(bf_lo(Ec.x) - Ms_);
        const float e1 = fexp2(bf_hi(Ec.x) - Ms_);
        const float e2 = fexp2(bf_lo(Ec.y) - Ms_);
        const float e3 = fexp2(bf_hi(Ec.y) - Ms_);
        al[0] = p0w0 * px0 * e0; al[1] = p0w1 * px0 * e1;
        al[2] = p0w2 * px0 * e2; al[3] = p0w3 * px0 * e3;
        t = 1;
        if (t < te) Ec = Eb[eidx(1, x, g)];
      }

      while (t < te && (t & 7)) {     // guarded entry until 8-aligned
        SCAN_STEP(t,
          if (t + 1 < te) { En_ = Eb[eidx((t + 1) & 31, x, g)]; })
        if ((t & 7) == 7) RENORM
        ++t;
      }

      const int ng = (te - t) >> 3;   // fast path: 8-step groups
      if (ng > 0) {
        u2 E1 = Eb[eidx((t + 1) & 31, x, g)];
        float snap = 0.f, Sready = 1.0f, rdy = 1.0f;
#pragma unroll 1
        for (int gi = 0; gi < ng; ++gi) {
#pragma unroll
          for (int k = 0; k < 8; ++k) {
            u2 E2 = Eb[eidx((t + k + 2) & 31, x, g)];   // 2-deep prefetch
            const float Ms_ = rdlane(Mrow, (t + k) & 31);
            float e0 = fexp2(bf_lo(Ec.x) - Ms_);
            float e1 = fexp2(bf_hi(Ec.x) - Ms_);
            float e2 = fexp2(bf_lo(Ec.y) - Ms_);
            float e3 = fexp2(bf_hi(Ec.y) - Ms_);
            if (k == 0) {       // apply previous group's renorm (off chain)
              e0 *= rdy; e1 *= rdy; e2 *= rdy; e3 *= rdy;
              acc += __log2f(Sready);
            }
            v4s a16 = mk4(pktrunc(al[0], al[1]), pktrunc(al[2], al[3]));
            v4f d1 = mfma16(a16, pwB, z4);
            v4s d16 = mk4(pktrunc(d1[0], d1[1]), pktrunc(d1[2], d1[3]));
            v4f d2 = mfma16(d16, pxB, z4);
            al[0] = d2[0] * e0; al[1] = d2[1] * e1;
            al[2] = d2[2] * e2; al[3] = d2[3] * e3;
            if (k == 0) snap = (al[0] + al[1]) + (al[2] + al[3]);
            if (k >= 1 && k <= 6)
              snap += __shfl_xor(snap, 1 << (k - 1), 64);
            if (k == 7) {
              Sready = fmaxf(snap, 1e-35f);
              rdy = __builtin_amdgcn_rcpf(Sready);
            }
            Ec = E1; E1 = E2;
          }
          t += 8;
        }
        acc += __log2f(Sready);     // flush pending renorm
        al[0] *= rdy; al[1] *= rdy; al[2] *= rdy; al[3] *= rdy;
      }

      while (t < te) {                // guarded tail
        SCAN_STEP(t,
          if (t + 1 < te) { En_ = Eb[eidx((t + 1) & 31, x, g)]; })
        if ((t & 7) == 7) RENORM
        ++t;
      }
#undef SCAN_STEP
#undef RENORM

      __syncthreads();   // scan(ch) done; producer's GEMM(ch+1) done
    }

    // ---------- finalize ----------
    float S = (al[0] + al[1]) + (al[2] + al[3]);
#pragma unroll
    for (int o = 1; o <= 32; o <<= 1) S += __shfl_xor(S, o, 64);
    S = fmaxf(S, 1e-35f);
    acc += __log2f(S);

#pragma unroll
    for (int o = 1; o <= 32; o <<= 1) msum += __shfl_xor(msum, o, 64);

    if (l == 0) out[b] = LN2 * (acc + msum);
  }
}

} // namespace

extern "C" void kernel_launch(void* const* d_in, const int* in_sizes, int n_in,
                              void* d_out, int out_size, void* d_ws, size_t ws_size,
                              hipStream_t stream) {
  const float* seq     = (const float*)d_in[0];
  const int*   lengths = (const int*)d_in[1];
  const float* pw      = (const float*)d_in[2];
  const float* px      = (const float*)d_in[3];
  const float* py      = (const float*)d_in[4];
  float*       out     = (float*)d_out;
  u2*          wsdif   = (u2*)d_ws;    // 32 KB shared B-frag table

  hipLaunchKernelGGL(fhmm_fwd, dim3(1024), dim3(128), 0, stream,
                     seq, lengths, pw, px, py, out, wsdif);
}